// Round 1
// baseline (478.011 us; speedup 1.0000x reference)
//
#include <hip/hip_runtime.h>
#include <hip/hip_bf16.h>

// Shapes are fixed by the problem instance (setup_inputs).
#define BB   8     // batch
#define TT   256   // steps
#define NH   8     // heads
#define CC   16    // 2*NH channels
#define HH   16
#define WW   32
#define LL   512   // HH*WW
#define DCH  32    // conv out channels
#define GC   8     // gate hidden channels (IN_CHS//2)

// ---------------------------------------------------------------------------
// K0: transpose conv_w (o,ic,ky,kx) -> cwT[k][ic][o] so the hot loop reads
// contiguous-in-o uniform addresses (scalar loads).
__global__ __launch_bounds__(256) void k_wtrans(const float* __restrict__ cw,
                                                float* __restrict__ cwT) {
  int i = blockIdx.x * 256 + threadIdx.x;  // 25*16*32 = 12800
  if (i < 25 * CC * DCH) {
    int o = i & 31;
    int ic = (i >> 5) & 15;
    int k = i >> 9;
    cwT[i] = cw[(o * CC + ic) * 25 + k];
  }
}

// ---------------------------------------------------------------------------
// K1: gating network. One block per (b,t). relu(conv3x3(attns)+b1) -> spatial
// mean -> sigmoid(W2 . pooled + b2) -> gate[bt][c]
__global__ __launch_bounds__(256) void k_gate(
    const float* __restrict__ prev, const float* __restrict__ curr,
    const float* __restrict__ gw1, const float* __restrict__ gb1,
    const float* __restrict__ gw2, const float* __restrict__ gb2,
    float* __restrict__ gate) {
  __shared__ float img[CC * LL];   // 32 KB
  __shared__ float red[GC * 4];
  __shared__ float pooled[GC];
  int bt = blockIdx.x;
  int b = bt / TT, t = bt % TT;
  int tid = threadIdx.x;

  for (int i = tid; i < CC * LL; i += 256) {
    int ch = i >> 9;            // /LL
    int pos = i & (LL - 1);
    const float* src = (ch < NH) ? prev : curr;
    img[i] = src[((size_t)(b * NH + (ch & 7)) * TT + t) * LL + pos];
  }
  __syncthreads();

  float ps[GC];
#pragma unroll
  for (int o = 0; o < GC; ++o) ps[o] = 0.f;

  for (int rep = 0; rep < 2; ++rep) {
    int p = tid + rep * 256;
    int y = p >> 5, x = p & 31;
    float acc[GC];
#pragma unroll
    for (int o = 0; o < GC; ++o) acc[o] = gb1[o];
    for (int ky = 0; ky < 3; ++ky) {
      int yy = y + ky - 1;
      if (yy < 0 || yy >= HH) continue;
      for (int kx = 0; kx < 3; ++kx) {
        int xx = x + kx - 1;
        if (xx < 0 || xx >= WW) continue;
#pragma unroll 4
        for (int ic = 0; ic < CC; ++ic) {
          float a = img[ic * LL + yy * WW + xx];
#pragma unroll
          for (int o = 0; o < GC; ++o)
            acc[o] = fmaf(a, gw1[((o * CC + ic) * 3 + ky) * 3 + kx], acc[o]);
        }
      }
    }
#pragma unroll
    for (int o = 0; o < GC; ++o) ps[o] += fmaxf(acc[o], 0.f);
  }

  int lane = tid & 63, wave = tid >> 6;
#pragma unroll
  for (int o = 0; o < GC; ++o) {
    float v = ps[o];
#pragma unroll
    for (int off = 32; off > 0; off >>= 1) v += __shfl_down(v, off, 64);
    if (lane == 0) red[o * 4 + wave] = v;
  }
  __syncthreads();
  if (tid < GC) {
    float s = red[tid * 4] + red[tid * 4 + 1] + red[tid * 4 + 2] + red[tid * 4 + 3];
    pooled[tid] = s * (1.0f / (float)LL);
  }
  __syncthreads();
  if (tid < CC) {
    float z = gb2[tid];
#pragma unroll
    for (int i = 0; i < GC; ++i) z = fmaf(pooled[i], gw2[tid * GC + i], z);
    gate[bt * CC + tid] = 1.f / (1.f + __expf(-z));
  }
}

// ---------------------------------------------------------------------------
// K2: exclusive cumsum over t of attns*gate, stored bf16. One thread per
// (b,c,l) column; a 256-thread block shares one (b,c) -> gate load is uniform.
__global__ __launch_bounds__(256) void k_cum(
    const float* __restrict__ prev, const float* __restrict__ curr,
    const float* __restrict__ gate, __hip_bfloat16* __restrict__ cum) {
  int idx = blockIdx.x * 256 + threadIdx.x;  // [0, B*C*L)
  int l = idx & (LL - 1);
  int c = (idx >> 9) & (CC - 1);
  int b = idx >> 13;
  const float* src = (c < NH) ? prev : curr;
  const float* a = src + (size_t)(b * NH + (c & 7)) * TT * LL + l;
  const float* g = gate + b * TT * CC + c;
  __hip_bfloat16* o = cum + (size_t)(b * CC + c) * TT * LL + l;
  float run = 0.f;
  for (int t = 0; t < TT; ++t) {
    float av = a[(size_t)t * LL];
    float gv = g[t * CC];
    *o = __float2bfloat16(run);   // exclusive
    o += LL;
    run = fmaf(av, gv, run);
  }
}

// ---------------------------------------------------------------------------
// K3: 5x5 conv 16->32 + bias + relu + mask-zero + 1x1 proj 32->8, writes
// pre-BN output in final [b*n][t][l] layout, accumulates BN sums.
__global__ __launch_bounds__(256) void k_cov(
    const __hip_bfloat16* __restrict__ cum, const float* __restrict__ cwT,
    const float* __restrict__ cb, const float* __restrict__ pw,
    const int* __restrict__ mask, float* __restrict__ out,
    float* __restrict__ sums) {
  __shared__ float img[CC * LL];   // 32 KB
  __shared__ float red[17 * 4];
  int bt = blockIdx.x;
  int b = bt / TT, t = bt % TT;
  int tid = threadIdx.x;

  for (int i = tid; i < CC * LL; i += 256) {
    int c = i >> 9;
    int pos = i & (LL - 1);
    img[i] = __bfloat162float(cum[((size_t)(b * CC + c) * TT + t) * LL + pos]);
  }
  __syncthreads();

  float psum[NH], psq[NH], pcnt = 0.f;
#pragma unroll
  for (int j = 0; j < NH; ++j) { psum[j] = 0.f; psq[j] = 0.f; }

  for (int rep = 0; rep < 2; ++rep) {
    int p = tid + rep * 256;
    int y = p >> 5, x = p & 31;
    float acc[DCH];
#pragma unroll
    for (int o = 0; o < DCH; ++o) acc[o] = cb[o];
    for (int ky = 0; ky < 5; ++ky) {
      int yy = y + ky - 2;
      if (yy < 0 || yy >= HH) continue;
      for (int kx = 0; kx < 5; ++kx) {
        int xx = x + kx - 2;
        if (xx < 0 || xx >= WW) continue;
        const float* wrow = cwT + (ky * 5 + kx) * (CC * DCH);
        const float* irow = img + yy * WW + xx;
#pragma unroll 4
        for (int ic = 0; ic < CC; ++ic) {
          float a = irow[ic * LL];
#pragma unroll
          for (int o = 0; o < DCH; ++o)
            acc[o] = fmaf(a, wrow[ic * DCH + o], acc[o]);  // weight = s_load
        }
      }
    }
    bool m = mask[b * LL + p] != 0;
    float keep = m ? 0.f : 1.f;
    pcnt += keep;
#pragma unroll
    for (int o = 0; o < DCH; ++o) acc[o] = fmaxf(acc[o], 0.f) * keep;
#pragma unroll
    for (int nh = 0; nh < NH; ++nh) {
      float s = 0.f;
#pragma unroll
      for (int o = 0; o < DCH; ++o) s = fmaf(acc[o], pw[nh * DCH + o], s);
      out[((size_t)(b * NH + nh) * TT + t) * LL + p] = s;
      psum[nh] += s;
      psq[nh] += s * s;
    }
  }

  int lane = tid & 63, wave = tid >> 6;
  float vals[17];
#pragma unroll
  for (int j = 0; j < NH; ++j) { vals[j] = psum[j]; vals[NH + j] = psq[j]; }
  vals[16] = pcnt;
#pragma unroll
  for (int j = 0; j < 17; ++j) {
    float v = vals[j];
#pragma unroll
    for (int off = 32; off > 0; off >>= 1) v += __shfl_down(v, off, 64);
    if (lane == 0) red[j * 4 + wave] = v;
  }
  __syncthreads();
  if (tid < 17) {
    float tot = red[tid * 4] + red[tid * 4 + 1] + red[tid * 4 + 2] + red[tid * 4 + 3];
    atomicAdd(&sums[tid], tot);
  }
}

// ---------------------------------------------------------------------------
// K4: masked BN normalize in-place on d_out. Masked positions keep 0.
__global__ __launch_bounds__(256) void k_bn(
    float* __restrict__ out, const float* __restrict__ sums,
    const int* __restrict__ mask, const float* __restrict__ gamma,
    const float* __restrict__ beta) {
  __shared__ float sc[NH], sh[NH];
  int tid = threadIdx.x;
  if (tid < NH) {
    float cnt = sums[16];
    float mean = sums[tid] / cnt;
    float var = sums[NH + tid] / cnt - mean * mean;
    float inv = rsqrtf(var + 1e-5f) * gamma[tid];
    sc[tid] = inv;
    sh[tid] = fmaf(-mean, inv, beta[tid]);
  }
  __syncthreads();
  size_t e = ((size_t)blockIdx.x * 256 + tid) * 4;  // 4 consecutive l
  int l = (int)(e & (LL - 1));
  int bn = (int)(e >> 17);  // TT*LL = 2^17
  int n = bn & 7, b = bn >> 3;
  const int4 mv = *(const int4*)(mask + b * LL + l);
  float4 v = *(float4*)(out + e);
  float s = sc[n], h = sh[n];
  v.x = mv.x ? v.x : fmaf(v.x, s, h);
  v.y = mv.y ? v.y : fmaf(v.y, s, h);
  v.z = mv.z ? v.z : fmaf(v.z, s, h);
  v.w = mv.w ? v.w : fmaf(v.w, s, h);
  *(float4*)(out + e) = v;
}

// ---------------------------------------------------------------------------
extern "C" void kernel_launch(void* const* d_in, const int* in_sizes, int n_in,
                              void* d_out, int out_size, void* d_ws, size_t ws_size,
                              hipStream_t stream) {
  const float* prev   = (const float*)d_in[0];
  const int*   mask   = (const int*)d_in[1];   // bool mask, assumed int32 transport
  const float* curr   = (const float*)d_in[3];
  const float* conv_w = (const float*)d_in[5];
  const float* conv_b = (const float*)d_in[6];
  const float* proj_w = (const float*)d_in[7];
  const float* g_w1   = (const float*)d_in[8];
  const float* g_b1   = (const float*)d_in[9];
  const float* g_w2   = (const float*)d_in[10];
  const float* g_b2   = (const float*)d_in[11];
  const float* bn_g   = (const float*)d_in[12];
  const float* bn_b   = (const float*)d_in[13];
  float* out = (float*)d_out;

  char* ws = (char*)d_ws;
  float* gate = (float*)(ws);                              // 2048*16*4 = 131072 B
  float* cwT  = (float*)(ws + 131072);                     // 12800*4  = 51200 B
  __hip_bfloat16* cum = (__hip_bfloat16*)(ws + 182272);    // 16777216*2 = 33554432 B
  float* sums = (float*)(ws + 182272 + 33554432);          // 17*4 B

  hipMemsetAsync(sums, 0, 17 * sizeof(float), stream);
  k_wtrans<<<50, 256, 0, stream>>>(conv_w, cwT);
  k_gate<<<BB * TT, 256, 0, stream>>>(prev, curr, g_w1, g_b1, g_w2, g_b2, gate);
  k_cum<<<(BB * CC * LL) / 256, 256, 0, stream>>>(prev, curr, gate, cum);
  k_cov<<<BB * TT, 256, 0, stream>>>(cum, cwT, conv_b, proj_w, mask, out, sums);
  k_bn<<<(BB * NH * TT * LL) / (256 * 4), 256, 0, stream>>>(out, sums, mask, bn_g, bn_b);
}

// Round 2
// 270.449 us; speedup vs baseline: 1.7675x; 1.7675x over previous
//
#include <hip/hip_runtime.h>
#include <hip/hip_bf16.h>

// Shapes fixed by the problem instance.
#define BB   8     // batch
#define TT   256   // steps
#define NH   8     // heads
#define CC   16    // 2*NH channels
#define HH   16
#define WW   32
#define LL   512   // HH*WW
#define DCH  32    // conv out channels
#define GC   8     // gate hidden channels

typedef __attribute__((ext_vector_type(8))) short s8b;    // 8 bf16 (4 VGPRs)
typedef __attribute__((ext_vector_type(4))) float f32x4;  // MFMA C/D

__device__ __forceinline__ short f2bf(float v) {
  __hip_bfloat16 h = __float2bfloat16(v);
  short s;
  __builtin_memcpy(&s, &h, 2);
  return s;
}

// ---------------------------------------------------------------------------
// K0: pack conv weights into MFMA B-fragment layout.
// bfrag[s][nt][lane][j] = W[k=s*32+quad*8+j][oc=nt*16+col], zero-padded k>=400.
// pwf[lane][j] = pwT[oc=quad*8+j][nh=col] (zero for col>=8).
__global__ __launch_bounds__(256) void k_gen(const float* __restrict__ cw,
                                             const float* __restrict__ pw,
                                             ushort* __restrict__ bfrag,
                                             ushort* __restrict__ pwf) {
  int idx = blockIdx.x * 256 + threadIdx.x;
  if (idx < 13312) {
    int j = idx & 7, lane = (idx >> 3) & 63, nt = (idx >> 9) & 1, s = idx >> 10;
    int quad = lane >> 4, col = lane & 15;
    int k = s * 32 + quad * 8 + j;
    int n = nt * 16 + col;
    float v = (k < 400) ? cw[(n * CC + (k & 15)) * 25 + (k >> 4)] : 0.f;
    bfrag[idx] = (ushort)f2bf(v);
  } else if (idx < 13312 + 512) {
    int i2 = idx - 13312;
    int j = i2 & 7, lane = i2 >> 3;
    int quad = lane >> 4, col = lane & 15;
    float v = (col < NH) ? pw[col * DCH + quad * 8 + j] : 0.f;
    pwf[i2] = (ushort)f2bf(v);
  }
}

// ---------------------------------------------------------------------------
// K1: gating network (unchanged from round 1).
__global__ __launch_bounds__(256) void k_gate(
    const float* __restrict__ prev, const float* __restrict__ curr,
    const float* __restrict__ gw1, const float* __restrict__ gb1,
    const float* __restrict__ gw2, const float* __restrict__ gb2,
    float* __restrict__ gate) {
  __shared__ float img[CC * LL];
  __shared__ float red[GC * 4];
  __shared__ float pooled[GC];
  int bt = blockIdx.x;
  int b = bt / TT, t = bt % TT;
  int tid = threadIdx.x;

  for (int i = tid; i < CC * LL; i += 256) {
    int ch = i >> 9;
    int pos = i & (LL - 1);
    const float* src = (ch < NH) ? prev : curr;
    img[i] = src[((size_t)(b * NH + (ch & 7)) * TT + t) * LL + pos];
  }
  __syncthreads();

  float ps[GC];
#pragma unroll
  for (int o = 0; o < GC; ++o) ps[o] = 0.f;

  for (int rep = 0; rep < 2; ++rep) {
    int p = tid + rep * 256;
    int y = p >> 5, x = p & 31;
    float acc[GC];
#pragma unroll
    for (int o = 0; o < GC; ++o) acc[o] = gb1[o];
    for (int ky = 0; ky < 3; ++ky) {
      int yy = y + ky - 1;
      if (yy < 0 || yy >= HH) continue;
      for (int kx = 0; kx < 3; ++kx) {
        int xx = x + kx - 1;
        if (xx < 0 || xx >= WW) continue;
#pragma unroll 4
        for (int ic = 0; ic < CC; ++ic) {
          float a = img[ic * LL + yy * WW + xx];
#pragma unroll
          for (int o = 0; o < GC; ++o)
            acc[o] = fmaf(a, gw1[((o * CC + ic) * 3 + ky) * 3 + kx], acc[o]);
        }
      }
    }
#pragma unroll
    for (int o = 0; o < GC; ++o) ps[o] += fmaxf(acc[o], 0.f);
  }

  int lane = tid & 63, wave = tid >> 6;
#pragma unroll
  for (int o = 0; o < GC; ++o) {
    float v = ps[o];
#pragma unroll
    for (int off = 32; off > 0; off >>= 1) v += __shfl_down(v, off, 64);
    if (lane == 0) red[o * 4 + wave] = v;
  }
  __syncthreads();
  if (tid < GC) {
    float s = red[tid * 4] + red[tid * 4 + 1] + red[tid * 4 + 2] + red[tid * 4 + 3];
    pooled[tid] = s * (1.0f / (float)LL);
  }
  __syncthreads();
  if (tid < CC) {
    float z = gb2[tid];
#pragma unroll
    for (int i = 0; i < GC; ++i) z = fmaf(pooled[i], gw2[tid * GC + i], z);
    gate[bt * CC + tid] = 1.f / (1.f + __expf(-z));
  }
}

// ---------------------------------------------------------------------------
// K2: exclusive cumsum over t of attns*gate, stored bf16 (unchanged).
__global__ __launch_bounds__(256) void k_cum(
    const float* __restrict__ prev, const float* __restrict__ curr,
    const float* __restrict__ gate, __hip_bfloat16* __restrict__ cum) {
  int idx = blockIdx.x * 256 + threadIdx.x;
  int l = idx & (LL - 1);
  int c = (idx >> 9) & (CC - 1);
  int b = idx >> 13;
  const float* src = (c < NH) ? prev : curr;
  const float* a = src + (size_t)(b * NH + (c & 7)) * TT * LL + l;
  const float* g = gate + b * TT * CC + c;
  __hip_bfloat16* o = cum + (size_t)(b * CC + c) * TT * LL + l;
  float run = 0.f;
  for (int t = 0; t < TT; ++t) {
    float av = a[(size_t)t * LL];
    float gv = g[t * CC];
    *o = __float2bfloat16(run);
    o += LL;
    run = fmaf(av, gv, run);
  }
}

// ---------------------------------------------------------------------------
// K3: MFMA implicit-GEMM 5x5 conv 16->32 (+bias+relu), mask, 1x1 proj as a
// second MFMA, BN-sum accumulation. One block = one (b,t) image.
__global__ __launch_bounds__(256, 2) void k_cov(
    const ushort* __restrict__ cum, const ushort* __restrict__ bfrag,
    const ushort* __restrict__ pwf, const float* __restrict__ cb,
    const int* __restrict__ mask, float* __restrict__ out,
    float* __restrict__ sums) {
  // smem union: phase A = imgp[720][16] bf16 (23040 B);
  //             phase B = scr: 4 waves * 128*33 f32 (67584 B)
  // tail: red[4][16][2] f32 (512 B) + redc[4] (16 B)
  __shared__ char smem[68112];
  ushort* imgp = (ushort*)smem;
  float* redp = (float*)(smem + 67584);
  float* redc = (float*)(smem + 67584 + 512);

  int tid = threadIdx.x;
  int lane = tid & 63, w = tid >> 6;
  int bt = blockIdx.x;
  int b = bt >> 8, t = bt & 255;
  int quad = lane >> 4, col = lane & 15;
  int qh = quad >> 1, icb = (quad & 1) * 8;

  // ---- stage: zero halo (208 pixels), fill interior transposed ----
  if (tid < 208) {
    int pix;
    if (tid < 144) {
      int r = tid / 36, c0 = tid - r * 36;
      int rr = (r < 2) ? r : r + 16;
      pix = rr * 36 + c0;
    } else {
      int j = tid - 144;
      int rr = 2 + (j >> 2);
      const int colt[4] = {0, 1, 34, 35};
      pix = rr * 36 + colt[j & 3];
    }
    s8b z = {0, 0, 0, 0, 0, 0, 0, 0};
    *(s8b*)(imgp + pix * 16) = z;
    *(s8b*)(imgp + pix * 16 + 8) = z;
  }
#pragma unroll
  for (int it = 0; it < 4; ++it) {
    int idx = it * 256 + tid;
    int c = idx >> 6, grp = idx & 63;
    uint4 v = *(const uint4*)(cum + ((size_t)(b * CC + c) * TT + t) * LL + grp * 8);
    ushort* u = (ushort*)&v;
    int p0 = grp * 8;
    int pixbase = ((p0 >> 5) + 2) * 36 + (p0 & 31) + 2;
#pragma unroll
    for (int e = 0; e < 8; ++e) imgp[(pixbase + e) * 16 + c] = u[e];
  }
  __syncthreads();

  // ---- K-loop: 13 steps of K=32 (2 kernel taps x 16 ic) ----
  f32x4 acc[8][2];
#pragma unroll
  for (int mi = 0; mi < 8; ++mi) {
    acc[mi][0] = (f32x4){0.f, 0.f, 0.f, 0.f};
    acc[mi][1] = (f32x4){0.f, 0.f, 0.f, 0.f};
  }
  int mtbase = w * 8;
  int pb16[8];
#pragma unroll
  for (int mi = 0; mi < 8; ++mi) {
    int mt = mtbase + mi;
    int y = mt >> 1, x = ((mt & 1) << 4) + col;
    pb16[mi] = (y * 36 + x) * 16 + icb;
  }
  const s8b* bfr = (const s8b*)bfrag;
  // off = ky*36+kx for taps 2s (even) and 2s+1 (odd); tap 25 clamped to 24.
  const int offE[13] = {0, 2, 4, 37, 39, 72, 74, 76, 109, 111, 144, 146, 148};
  const int offO[13] = {1, 3, 36, 38, 40, 73, 75, 108, 110, 112, 145, 147, 148};
#pragma unroll
  for (int s = 0; s < 13; ++s) {
    s8b bf0 = bfr[(s * 2) * 64 + lane];
    s8b bf1 = bfr[(s * 2 + 1) * 64 + lane];
    int off16 = (qh ? offO[s] : offE[s]) * 16;
#pragma unroll
    for (int mi = 0; mi < 8; ++mi) {
      s8b af = *(const s8b*)(imgp + pb16[mi] + off16);
      acc[mi][0] = __builtin_amdgcn_mfma_f32_16x16x32_bf16(af, bf0, acc[mi][0], 0, 0, 0);
      acc[mi][1] = __builtin_amdgcn_mfma_f32_16x16x32_bf16(af, bf1, acc[mi][1], 0, 0, 0);
    }
  }
  __syncthreads();  // imgp dead; smem becomes scr

  // ---- epilogue phase 1: bias+relu, C tiles -> scr[pos][oc] (stride 33) ----
  float* scr = (float*)smem + w * (128 * 33);
  float cb0 = cb[col], cb1 = cb[col + 16];
#pragma unroll
  for (int mi = 0; mi < 8; ++mi) {
#pragma unroll
    for (int r = 0; r < 4; ++r) {
      int row = mi * 16 + quad * 4 + r;
      scr[row * 33 + col] = fmaxf(acc[mi][0][r] + cb0, 0.f);
      scr[row * 33 + col + 16] = fmaxf(acc[mi][1][r] + cb1, 0.f);
    }
  }
  __syncthreads();

  // ---- epilogue phase 2: proj via MFMA, mask, store, BN sums ----
  s8b pf = ((const s8b*)pwf)[lane];
  float psum = 0.f, psq = 0.f, pcnt = 0.f;
  float* outbase = out + ((size_t)(b * NH + col) * TT + t) * LL;  // col<8 only
  const int* mrow = mask + b * LL;
#pragma unroll
  for (int mi = 0; mi < 8; ++mi) {
    int mt = mtbase + mi;
    s8b a2;
#pragma unroll
    for (int j = 0; j < 8; ++j)
      a2[j] = f2bf(scr[(mi * 16 + col) * 33 + quad * 8 + j]);
    f32x4 zero = {0.f, 0.f, 0.f, 0.f};
    f32x4 d2 = __builtin_amdgcn_mfma_f32_16x16x32_bf16(a2, pf, zero, 0, 0, 0);
    int4 m4 = *(const int4*)(mrow + mt * 16 + quad * 4);
    float k0 = m4.x ? 0.f : 1.f;
    float k1 = m4.y ? 0.f : 1.f;
    float k2 = m4.z ? 0.f : 1.f;
    float k3 = m4.w ? 0.f : 1.f;
    if (col < NH) {
      float* op = outbase + mt * 16 + quad * 4;
      float v0 = d2[0] * k0; op[0] = v0; psum += v0; psq += v0 * v0;
      float v1 = d2[1] * k1; op[1] = v1; psum += v1; psq += v1 * v1;
      float v2 = d2[2] * k2; op[2] = v2; psum += v2; psq += v2 * v2;
      float v3 = d2[3] * k3; op[3] = v3; psum += v3; psq += v3 * v3;
    }
    if (col == 0) pcnt += k0 + k1 + k2 + k3;
  }

  // reduce across quads (lanes stride 16), then block-level atomics
  psum += __shfl_down(psum, 16, 64); psum += __shfl_down(psum, 32, 64);
  psq  += __shfl_down(psq, 16, 64);  psq  += __shfl_down(psq, 32, 64);
  pcnt += __shfl_down(pcnt, 16, 64); pcnt += __shfl_down(pcnt, 32, 64);
  if (lane < 16) {
    redp[(w * 16 + lane) * 2] = psum;
    redp[(w * 16 + lane) * 2 + 1] = psq;
    if (lane == 0) redc[w] = pcnt;
  }
  __syncthreads();
  if (tid < 17) {
    float v;
    if (tid < 8) {
      v = redp[tid * 2] + redp[(16 + tid) * 2] + redp[(32 + tid) * 2] + redp[(48 + tid) * 2];
    } else if (tid < 16) {
      int nh = tid - 8;
      v = redp[nh * 2 + 1] + redp[(16 + nh) * 2 + 1] + redp[(32 + nh) * 2 + 1] + redp[(48 + nh) * 2 + 1];
    } else {
      v = redc[0] + redc[1] + redc[2] + redc[3];
    }
    atomicAdd(&sums[tid], v);
  }
}

// ---------------------------------------------------------------------------
// K4: masked BN normalize in-place (unchanged).
__global__ __launch_bounds__(256) void k_bn(
    float* __restrict__ out, const float* __restrict__ sums,
    const int* __restrict__ mask, const float* __restrict__ gamma,
    const float* __restrict__ beta) {
  __shared__ float sc[NH], sh[NH];
  int tid = threadIdx.x;
  if (tid < NH) {
    float cnt = sums[16];
    float mean = sums[tid] / cnt;
    float var = sums[NH + tid] / cnt - mean * mean;
    float inv = rsqrtf(var + 1e-5f) * gamma[tid];
    sc[tid] = inv;
    sh[tid] = fmaf(-mean, inv, beta[tid]);
  }
  __syncthreads();
  size_t e = ((size_t)blockIdx.x * 256 + tid) * 4;
  int l = (int)(e & (LL - 1));
  int bn = (int)(e >> 17);
  int n = bn & 7, b = bn >> 3;
  const int4 mv = *(const int4*)(mask + b * LL + l);
  float4 v = *(float4*)(out + e);
  float s = sc[n], h = sh[n];
  v.x = mv.x ? v.x : fmaf(v.x, s, h);
  v.y = mv.y ? v.y : fmaf(v.y, s, h);
  v.z = mv.z ? v.z : fmaf(v.z, s, h);
  v.w = mv.w ? v.w : fmaf(v.w, s, h);
  *(float4*)(out + e) = v;
}

// ---------------------------------------------------------------------------
extern "C" void kernel_launch(void* const* d_in, const int* in_sizes, int n_in,
                              void* d_out, int out_size, void* d_ws, size_t ws_size,
                              hipStream_t stream) {
  const float* prev   = (const float*)d_in[0];
  const int*   mask   = (const int*)d_in[1];
  const float* curr   = (const float*)d_in[3];
  const float* conv_w = (const float*)d_in[5];
  const float* conv_b = (const float*)d_in[6];
  const float* proj_w = (const float*)d_in[7];
  const float* g_w1   = (const float*)d_in[8];
  const float* g_b1   = (const float*)d_in[9];
  const float* g_w2   = (const float*)d_in[10];
  const float* g_b2   = (const float*)d_in[11];
  const float* bn_g   = (const float*)d_in[12];
  const float* bn_b   = (const float*)d_in[13];
  float* out = (float*)d_out;

  char* ws = (char*)d_ws;
  float* gate = (float*)(ws);                              // 131072 B
  ushort* bfrag = (ushort*)(ws + 131072);                  // 26624 B
  ushort* pwf = (ushort*)(ws + 157696);                    // 1024 B
  __hip_bfloat16* cumb = (__hip_bfloat16*)(ws + 158720);   // 33554432 B
  float* sums = (float*)(ws + 158720 + 33554432);          // 68 B

  hipMemsetAsync(sums, 0, 17 * sizeof(float), stream);
  k_gen<<<54, 256, 0, stream>>>(conv_w, proj_w, bfrag, pwf);
  k_gate<<<BB * TT, 256, 0, stream>>>(prev, curr, g_w1, g_b1, g_w2, g_b2, gate);
  k_cum<<<(BB * CC * LL) / 256, 256, 0, stream>>>(prev, curr, gate, cumb);
  k_cov<<<BB * TT, 256, 0, stream>>>((const ushort*)cumb, bfrag, pwf, conv_b,
                                     mask, out, sums);
  k_bn<<<(BB * NH * TT * LL) / (256 * 4), 256, 0, stream>>>(out, sums, mask, bn_g, bn_b);
}

// Round 4
// 222.980 us; speedup vs baseline: 2.1437x; 1.2129x over previous
//
#include <hip/hip_runtime.h>
#include <hip/hip_bf16.h>

// Shapes fixed by the problem instance.
#define BB   8
#define TT   256
#define NH   8
#define CC   16
#define HH   16
#define WW   32
#define LL   512
#define DCH  32
#define GC   8

typedef __attribute__((ext_vector_type(8))) short s8b;
typedef __attribute__((ext_vector_type(4))) float f32x4;

__device__ __forceinline__ ushort f2bfu(float v) {
  __hip_bfloat16 h = __float2bfloat16(v);
  ushort s;
  __builtin_memcpy(&s, &h, 2);
  return s;
}
__device__ __forceinline__ float bf2f(ushort u) {
  unsigned w = ((unsigned)u) << 16;
  float f;
  __builtin_memcpy(&f, &w, 4);
  return f;
}

// ---------------------------------------------------------------------------
// K0: pack weights into MFMA B-fragment layouts.
// bfrag (5x5 conv, 16->32): [s<13][nt<2][lane][j], k=s*32+quad*8+j, oc=nt*16+col
// pwf   (1x1 proj, 32->8):  [lane][j], k=quad*8+j (oc), n=col (nh, 0 for col>=8)
// bfragG(3x3 gate, 16->8):  [s<5][lane][j], k=s*32+quad*8+j, oc=col (0 for col>=8)
__global__ __launch_bounds__(256) void k_gen(const float* __restrict__ cw,
                                             const float* __restrict__ pw,
                                             const float* __restrict__ gw1,
                                             ushort* __restrict__ bfrag,
                                             ushort* __restrict__ pwf,
                                             ushort* __restrict__ bfragG) {
  int idx = blockIdx.x * 256 + threadIdx.x;
  if (idx < 13312) {
    int j = idx & 7, lane = (idx >> 3) & 63, nt = (idx >> 9) & 1, s = idx >> 10;
    int quad = lane >> 4, col = lane & 15;
    int k = s * 32 + quad * 8 + j;
    int n = nt * 16 + col;
    float v = (k < 400) ? cw[(n * CC + (k & 15)) * 25 + (k >> 4)] : 0.f;
    bfrag[idx] = f2bfu(v);
  } else if (idx < 13824) {
    int i2 = idx - 13312;
    int j = i2 & 7, lane = i2 >> 3;
    int quad = lane >> 4, col = lane & 15;
    float v = (col < NH) ? pw[col * DCH + quad * 8 + j] : 0.f;
    pwf[i2] = f2bfu(v);
  } else if (idx < 16384) {
    int i3 = idx - 13824;
    int j = i3 & 7, lane = (i3 >> 3) & 63, s = i3 >> 9;  // s<5
    int quad = lane >> 4, col = lane & 15;
    int k = s * 32 + quad * 8 + j;
    float v = 0.f;
    if (k < 144 && col < GC) v = gw1[(col * CC + (k & 15)) * 9 + (k >> 4)];
    bfragG[i3] = f2bfu(v);
  }
}

// ---------------------------------------------------------------------------
// K1: gate network via MFMA (3x3 conv 16->8 + pool + FC + sigmoid), then
// writes gated = bf16(attn * gate) in [b][c][t][l] layout. One block = (b,t).
// Image LDS layout: pair-interleaved img[ic/2][18 rows][48 slots][2], bf16.
// Interior x at slot 8+x (rows r=y+1), halo zero.
__global__ __launch_bounds__(256) void k_gate(
    const float* __restrict__ prev, const float* __restrict__ curr,
    const ushort* __restrict__ bfragG, const float* __restrict__ gb1,
    const float* __restrict__ gw2, const float* __restrict__ gb2,
    ushort* __restrict__ gated) {
  __shared__ __align__(16) ushort img[8 * 1728];  // 8 pairs * 864 pix * 2
  __shared__ float redg[64];
  __shared__ float pooled[16];
  __shared__ float gateS[16];

  int tid = threadIdx.x;
  int lane = tid & 63, w = tid >> 6;
  int bt = blockIdx.x;
  int b = bt >> 8, t = bt & 255;
  int quad = lane >> 4, col = lane & 15;
  int qh = quad >> 1, icb = (quad & 1) * 8;

  // zero image: 8*1728 ushorts = 27648 B = 1728 uint4  (round-3 bug: was 864)
  for (int i = tid; i < 1728; i += 256) ((uint4*)img)[i] = (uint4){0, 0, 0, 0};
  __syncthreads();

  // stage: pair-interleaved fill, contiguous b64 writes
#pragma unroll
  for (int it = 0; it < 4; ++it) {
#pragma unroll
    for (int e = 0; e < 2; ++e) {
      int W = ((it * 4 + w) * 2 + e) * 64 + lane;  // 0..2047
      int cp = W >> 8, pp = W & 255;
      int l0 = pp * 2;
      const float* src = (cp < 4) ? prev : curr;
      int chb = (cp & 3) * 2;
      const float* p0 = src + ((size_t)(b * NH + chb) * TT + t) * LL + l0;
      float2 fa = *(const float2*)p0;
      float2 fb = *(const float2*)(p0 + TT * LL);
      unsigned lo = (unsigned)f2bfu(fa.x) | ((unsigned)f2bfu(fb.x) << 16);
      unsigned hi = (unsigned)f2bfu(fa.y) | ((unsigned)f2bfu(fb.y) << 16);
      int r = l0 >> 5, x = l0 & 31;
      int slot = (r + 1) * 48 + 8 + x;
      *(uint2*)&img[cp * 1728 + slot * 2] = (uint2){lo, hi};
    }
  }
  __syncthreads();

  // K-loop: 5 steps of K=32 (2 taps x 16 ic)
  f32x4 acc[8];
#pragma unroll
  for (int mi = 0; mi < 8; ++mi) acc[mi] = (f32x4){0.f, 0.f, 0.f, 0.f};
  int mtbase = w * 8;
  int ab[8];
#pragma unroll
  for (int mi = 0; mi < 8; ++mi) {
    int mt = mtbase + mi;
    int py = mt >> 1, px = ((mt & 1) << 4) + col;
    ab[mi] = (icb >> 1) * 1728 + (py * 48 + 7 + px) * 2;
  }
  const int offE[5] = {0, 2, 49, 96, 98};
  const int offO[5] = {1, 48, 50, 97, 98};  // last = dummy (B zero)
  const s8b* bG = (const s8b*)bfragG;
#pragma unroll
  for (int s = 0; s < 5; ++s) {
    s8b bf = bG[s * 64 + lane];
    int off2 = (qh ? offO[s] : offE[s]) * 2;
#pragma unroll
    for (int mi = 0; mi < 8; ++mi) {
      union { unsigned u[4]; s8b v; } A;
      int a0 = ab[mi] + off2;
#pragma unroll
      for (int p = 0; p < 4; ++p) A.u[p] = *(const unsigned*)&img[a0 + p * 1728];
      acc[mi] = __builtin_amdgcn_mfma_f32_16x16x32_bf16(A.v, bf, acc[mi], 0, 0, 0);
    }
  }

  // pool: mean over 512 pixels of relu(conv + b1), per oc (=col)
  float gb1c = (col < GC) ? gb1[col] : 0.f;
  float s = 0.f;
#pragma unroll
  for (int mi = 0; mi < 8; ++mi)
#pragma unroll
    for (int r = 0; r < 4; ++r) s += fmaxf(acc[mi][r] + gb1c, 0.f);
  s += __shfl_down(s, 16, 64);
  s += __shfl_down(s, 32, 64);
  if (lane < 16) redg[w * 16 + lane] = s;
  __syncthreads();
  if (tid < 16)
    pooled[tid] = (redg[tid] + redg[16 + tid] + redg[32 + tid] + redg[48 + tid]) *
                  (1.0f / (float)LL);
  __syncthreads();
  if (tid < 16) {
    float z = gb2[tid];
#pragma unroll
    for (int i = 0; i < GC; ++i) z = fmaf(pooled[i], gw2[tid * GC + i], z);
    gateS[tid] = 1.f / (1.f + __expf(-z));
  }
  __syncthreads();

  // gated write: reload attn f32 (L2-hot), multiply by gate, store bf16
#pragma unroll
  for (int it = 0; it < 4; ++it) {
    int c = it * 4 + w;
    float g = gateS[c];
    const float* src = (c < NH) ? prev : curr;
    const float* p0 = src + ((size_t)(b * NH + (c & 7)) * TT + t) * LL + lane * 8;
    float4 v0 = *(const float4*)p0;
    float4 v1 = *(const float4*)(p0 + 4);
    ushort u[8];
    u[0] = f2bfu(v0.x * g); u[1] = f2bfu(v0.y * g);
    u[2] = f2bfu(v0.z * g); u[3] = f2bfu(v0.w * g);
    u[4] = f2bfu(v1.x * g); u[5] = f2bfu(v1.y * g);
    u[6] = f2bfu(v1.z * g); u[7] = f2bfu(v1.w * g);
    uint4 ov;
    __builtin_memcpy(&ov, u, 16);
    *(uint4*)(gated + ((size_t)(b * CC + c) * TT + t) * LL + lane * 8) = ov;
  }
}

// ---------------------------------------------------------------------------
// K2a: per-chunk sums of gated (8 chunks of 32 t).
__global__ __launch_bounds__(256) void k_cumA(const ushort* __restrict__ gated,
                                              float* __restrict__ csum) {
  int idx = blockIdx.x * 256 + threadIdx.x;
  int l = idx & 511, tc = (idx >> 9) & 7, c = (idx >> 12) & 15, b = idx >> 16;
  const ushort* g = gated + ((size_t)(b * CC + c) * TT + tc * 32) * LL + l;
  float s = 0.f;
#pragma unroll 8
  for (int j = 0; j < 32; ++j) s += bf2f(g[j * LL]);
  csum[((b * CC + c) * 8 + tc) * LL + l] = s;
}

// K2b: in-place exclusive scan over t within each chunk + chunk offsets.
__global__ __launch_bounds__(256) void k_cumB(ushort* __restrict__ gated,
                                              const float* __restrict__ csum) {
  int idx = blockIdx.x * 256 + threadIdx.x;
  int l = idx & 511, tc = (idx >> 9) & 7, c = (idx >> 12) & 15, b = idx >> 16;
  float run = 0.f;
  const float* cs = csum + ((b * CC + c) * 8) * LL + l;
  for (int u = 0; u < tc; ++u) run += cs[u * LL];
  ushort* g = gated + ((size_t)(b * CC + c) * TT + tc * 32) * LL + l;
#pragma unroll 4
  for (int j = 0; j < 32; ++j) {
    ushort raw = g[j * LL];
    float v = bf2f(raw);
    g[j * LL] = f2bfu(run);  // exclusive
    run += v;
  }
}

// ---------------------------------------------------------------------------
// K3: MFMA implicit-GEMM 5x5 conv 16->32 (+bias+relu), mask, 1x1 proj MFMA,
// BN-sum accumulation. One block = one (b,t) image.
// img: pair-interleaved [ic/2][20 rows][48 slots][2] bf16; interior x at 8+x,
// rows r=y+2; halo zero. scr: per-wave [32 oc][18] bf16 (no barrier needed).
__global__ __launch_bounds__(256, 2) void k_cov(
    const ushort* __restrict__ cum, const ushort* __restrict__ bfrag,
    const ushort* __restrict__ pwf, const float* __restrict__ cb,
    const int* __restrict__ mask, float* __restrict__ out,
    float* __restrict__ sums) {
  __shared__ __align__(16) ushort img[8 * 1920];  // 8 pairs * 960 pix * 2
  __shared__ __align__(16) ushort scr[4 * 576];   // per wave 32*18
  __shared__ float redp[128];
  __shared__ float redc[4];

  int tid = threadIdx.x;
  int lane = tid & 63, w = tid >> 6;
  int bt = blockIdx.x;
  int b = bt >> 8, t = bt & 255;
  int quad = lane >> 4, col = lane & 15;
  int qh = quad >> 1, icb = (quad & 1) * 8;

  // zero image: 8*1920 ushorts = 30720 B = 1920 uint4  (round-3 bug: was 960)
  for (int i = tid; i < 1920; i += 256) ((uint4*)img)[i] = (uint4){0, 0, 0, 0};
  __syncthreads();

  // stage (raw bf16 copy, pair-interleave, contiguous b64 writes)
#pragma unroll
  for (int it = 0; it < 4; ++it) {
#pragma unroll
    for (int e = 0; e < 2; ++e) {
      int W = ((it * 4 + w) * 2 + e) * 64 + lane;  // 0..2047
      int cp = W >> 8, pp = W & 255;
      int l0 = pp * 2;
      const ushort* p0 = cum + ((size_t)(b * CC + cp * 2) * TT + t) * LL + l0;
      unsigned a = *(const unsigned*)p0;
      unsigned bb2 = *(const unsigned*)(p0 + TT * LL);
      unsigned lo = (a & 0xFFFFu) | (bb2 << 16);
      unsigned hi = (a >> 16) | (bb2 & 0xFFFF0000u);
      int r = l0 >> 5, x = l0 & 31;
      int slot = (r + 2) * 48 + 8 + x;
      *(uint2*)&img[cp * 1920 + slot * 2] = (uint2){lo, hi};
    }
  }
  __syncthreads();

  // K-loop: 13 steps of K=32 (2 taps x 16 ic)
  f32x4 acc[8][2];
#pragma unroll
  for (int mi = 0; mi < 8; ++mi) {
    acc[mi][0] = (f32x4){0.f, 0.f, 0.f, 0.f};
    acc[mi][1] = (f32x4){0.f, 0.f, 0.f, 0.f};
  }
  int mtbase = w * 8;
  int ab[8];
#pragma unroll
  for (int mi = 0; mi < 8; ++mi) {
    int mt = mtbase + mi;
    int py = mt >> 1, px = ((mt & 1) << 4) + col;
    ab[mi] = (icb >> 1) * 1920 + (py * 48 + 6 + px) * 2;
  }
  const int offE[13] = {0, 2, 4, 49, 51, 96, 98, 100, 145, 147, 192, 194, 196};
  const int offO[13] = {1, 3, 48, 50, 52, 97, 99, 144, 146, 148, 193, 195, 196};
  const s8b* bfr = (const s8b*)bfrag;
#pragma unroll
  for (int s = 0; s < 13; ++s) {
    s8b bf0 = bfr[(s * 2) * 64 + lane];
    s8b bf1 = bfr[(s * 2 + 1) * 64 + lane];
    int off2 = (qh ? offO[s] : offE[s]) * 2;
#pragma unroll
    for (int mi = 0; mi < 8; ++mi) {
      union { unsigned u[4]; s8b v; } A;
      int a0 = ab[mi] + off2;
#pragma unroll
      for (int p = 0; p < 4; ++p) A.u[p] = *(const unsigned*)&img[a0 + p * 1920];
      acc[mi][0] = __builtin_amdgcn_mfma_f32_16x16x32_bf16(A.v, bf0, acc[mi][0], 0, 0, 0);
      acc[mi][1] = __builtin_amdgcn_mfma_f32_16x16x32_bf16(A.v, bf1, acc[mi][1], 0, 0, 0);
    }
  }

  // epilogue: per mi, wave-private scr round-trip (C-layout -> A-layout),
  // proj MFMA, mask, store, BN partials. No barriers needed.
  int wb = w * 576;
  float cb0 = cb[col], cb1 = cb[col + 16];
  s8b pf = ((const s8b*)pwf)[lane];
  float psum = 0.f, psq = 0.f, pcnt = 0.f;
  float* outbase = out + ((size_t)(b * NH + col) * TT + t) * LL;  // col<8 only
  const int* mrow = mask + b * LL;
#pragma unroll
  for (int mi = 0; mi < 8; ++mi) {
    int mt = mtbase + mi;
#pragma unroll
    for (int r = 0; r < 4; ++r) {
      int p = quad * 4 + r;
      scr[wb + col * 18 + p] = f2bfu(fmaxf(acc[mi][0][r] + cb0, 0.f));
      scr[wb + (col + 16) * 18 + p] = f2bfu(fmaxf(acc[mi][1][r] + cb1, 0.f));
    }
    ushort u[8];
#pragma unroll
    for (int e = 0; e < 8; ++e) u[e] = scr[wb + (quad * 8 + e) * 18 + col];
    s8b a2;
    __builtin_memcpy(&a2, u, 16);
    f32x4 zero = {0.f, 0.f, 0.f, 0.f};
    f32x4 d2 = __builtin_amdgcn_mfma_f32_16x16x32_bf16(a2, pf, zero, 0, 0, 0);
    int4 m4 = *(const int4*)(mrow + mt * 16 + quad * 4);
    float k0 = m4.x ? 0.f : 1.f;
    float k1 = m4.y ? 0.f : 1.f;
    float k2 = m4.z ? 0.f : 1.f;
    float k3 = m4.w ? 0.f : 1.f;
    if (col < NH) {
      float* op = outbase + mt * 16 + quad * 4;
      float v0 = d2[0] * k0; op[0] = v0; psum += v0; psq += v0 * v0;
      float v1 = d2[1] * k1; op[1] = v1; psum += v1; psq += v1 * v1;
      float v2 = d2[2] * k2; op[2] = v2; psum += v2; psq += v2 * v2;
      float v3 = d2[3] * k3; op[3] = v3; psum += v3; psq += v3 * v3;
    }
    if (col == 0) pcnt += k0 + k1 + k2 + k3;
  }

  psum += __shfl_down(psum, 16, 64); psum += __shfl_down(psum, 32, 64);
  psq  += __shfl_down(psq, 16, 64);  psq  += __shfl_down(psq, 32, 64);
  pcnt += __shfl_down(pcnt, 16, 64); pcnt += __shfl_down(pcnt, 32, 64);
  if (lane < 16) {
    redp[(w * 16 + lane) * 2] = psum;
    redp[(w * 16 + lane) * 2 + 1] = psq;
    if (lane == 0) redc[w] = pcnt;
  }
  __syncthreads();
  if (tid < 17) {
    float v;
    if (tid < 8) {
      v = redp[tid * 2] + redp[(16 + tid) * 2] + redp[(32 + tid) * 2] + redp[(48 + tid) * 2];
    } else if (tid < 16) {
      int nh = tid - 8;
      v = redp[nh * 2 + 1] + redp[(16 + nh) * 2 + 1] + redp[(32 + nh) * 2 + 1] + redp[(48 + nh) * 2 + 1];
    } else {
      v = redc[0] + redc[1] + redc[2] + redc[3];
    }
    atomicAdd(&sums[tid], v);
  }
}

// ---------------------------------------------------------------------------
// K4: masked BN normalize in-place.
__global__ __launch_bounds__(256) void k_bn(
    float* __restrict__ out, const float* __restrict__ sums,
    const int* __restrict__ mask, const float* __restrict__ gamma,
    const float* __restrict__ beta) {
  __shared__ float sc[NH], sh[NH];
  int tid = threadIdx.x;
  if (tid < NH) {
    float cnt = sums[16];
    float mean = sums[tid] / cnt;
    float var = sums[NH + tid] / cnt - mean * mean;
    float inv = rsqrtf(var + 1e-5f) * gamma[tid];
    sc[tid] = inv;
    sh[tid] = fmaf(-mean, inv, beta[tid]);
  }
  __syncthreads();
  size_t e = ((size_t)blockIdx.x * 256 + tid) * 4;
  int l = (int)(e & (LL - 1));
  int bn = (int)(e >> 17);
  int n = bn & 7, b = bn >> 3;
  const int4 mv = *(const int4*)(mask + b * LL + l);
  float4 v = *(float4*)(out + e);
  float s = sc[n], h = sh[n];
  v.x = mv.x ? v.x : fmaf(v.x, s, h);
  v.y = mv.y ? v.y : fmaf(v.y, s, h);
  v.z = mv.z ? v.z : fmaf(v.z, s, h);
  v.w = mv.w ? v.w : fmaf(v.w, s, h);
  *(float4*)(out + e) = v;
}

// ---------------------------------------------------------------------------
extern "C" void kernel_launch(void* const* d_in, const int* in_sizes, int n_in,
                              void* d_out, int out_size, void* d_ws, size_t ws_size,
                              hipStream_t stream) {
  const float* prev   = (const float*)d_in[0];
  const int*   mask   = (const int*)d_in[1];
  const float* curr   = (const float*)d_in[3];
  const float* conv_w = (const float*)d_in[5];
  const float* conv_b = (const float*)d_in[6];
  const float* proj_w = (const float*)d_in[7];
  const float* g_w1   = (const float*)d_in[8];
  const float* g_b1   = (const float*)d_in[9];
  const float* g_w2   = (const float*)d_in[10];
  const float* g_b2   = (const float*)d_in[11];
  const float* bn_g   = (const float*)d_in[12];
  const float* bn_b   = (const float*)d_in[13];
  float* out = (float*)d_out;

  char* ws = (char*)d_ws;
  ushort* bfrag  = (ushort*)(ws);                 // 26624 B
  ushort* pwf    = (ushort*)(ws + 26624);         // 1024 B
  ushort* bfragG = (ushort*)(ws + 27648);         // 5120 B
  float*  sums   = (float*)(ws + 32768);          // 68 B
  ushort* gated  = (ushort*)(ws + 65536);         // 33554432 B (becomes cum)
  float*  csum   = (float*)(ws + 65536 + 33554432);  // 2097152 B

  hipMemsetAsync(sums, 0, 17 * sizeof(float), stream);
  k_gen<<<64, 256, 0, stream>>>(conv_w, proj_w, g_w1, bfrag, pwf, bfragG);
  k_gate<<<BB * TT, 256, 0, stream>>>(prev, curr, bfragG, g_b1, g_w2, g_b2, gated);
  k_cumA<<<2048, 256, 0, stream>>>(gated, csum);
  k_cumB<<<2048, 256, 0, stream>>>(gated, csum);
  k_cov<<<BB * TT, 256, 0, stream>>>(gated, bfrag, pwf, conv_b, mask, out, sums);
  k_bn<<<(BB * NH * TT * LL) / (256 * 4), 256, 0, stream>>>(out, sums, mask, bn_g, bn_b);
}

// Round 5
// 216.714 us; speedup vs baseline: 2.2057x; 1.0289x over previous
//
#include <hip/hip_runtime.h>
#include <hip/hip_bf16.h>

// Shapes fixed by the problem instance.
#define BB   8
#define TT   256
#define NH   8
#define CC   16
#define HH   16
#define WW   32
#define LL   512
#define DCH  32
#define GC   8

// LDS image pair strides (ushorts). 1928*2 B => bank shift 4/pair, so quads
// 0/1 (pairs p and p+4) tile disjoint 16-bank sets: every A-read is 2-way.
#define PSC  1928   // k_cov: 960 pix + 4 pad slots
#define PSG  1736   // k_gate: 864 pix + 4 pad slots

typedef __attribute__((ext_vector_type(8))) short s8b;
typedef __attribute__((ext_vector_type(4))) float f32x4;

__device__ __forceinline__ ushort f2bfu(float v) {
  __hip_bfloat16 h = __float2bfloat16(v);
  ushort s;
  __builtin_memcpy(&s, &h, 2);
  return s;
}

// ---------------------------------------------------------------------------
// K0: pack weights into MFMA B-fragment layouts; zero BN sums.
__global__ __launch_bounds__(256) void k_gen(const float* __restrict__ cw,
                                             const float* __restrict__ pw,
                                             const float* __restrict__ gw1,
                                             ushort* __restrict__ bfrag,
                                             ushort* __restrict__ pwf,
                                             ushort* __restrict__ bfragG,
                                             float* __restrict__ sums) {
  int idx = blockIdx.x * 256 + threadIdx.x;
  if (idx < 17) sums[idx] = 0.f;
  if (idx < 13312) {
    int j = idx & 7, lane = (idx >> 3) & 63, nt = (idx >> 9) & 1, s = idx >> 10;
    int quad = lane >> 4, col = lane & 15;
    int k = s * 32 + quad * 8 + j;
    int n = nt * 16 + col;
    float v = (k < 400) ? cw[(n * CC + (k & 15)) * 25 + (k >> 4)] : 0.f;
    bfrag[idx] = f2bfu(v);
  } else if (idx < 13824) {
    int i2 = idx - 13312;
    int j = i2 & 7, lane = i2 >> 3;
    int quad = lane >> 4, col = lane & 15;
    float v = (col < NH) ? pw[col * DCH + quad * 8 + j] : 0.f;
    pwf[i2] = f2bfu(v);
  } else if (idx < 16384) {
    int i3 = idx - 13824;
    int j = i3 & 7, lane = (i3 >> 3) & 63, s = i3 >> 9;  // s<5
    int quad = lane >> 4, col = lane & 15;
    int k = s * 32 + quad * 8 + j;
    float v = 0.f;
    if (k < 144 && col < GC) v = gw1[(col * CC + (k & 15)) * 9 + (k >> 4)];
    bfragG[i3] = f2bfu(v);
  }
}

// ---------------------------------------------------------------------------
// K1: gate network via MFMA (3x3 conv 16->8 + pool + FC + sigmoid).
// Writes ONLY gate2[b][c][t] (tiny). One block = (b,t).
__global__ __launch_bounds__(256) void k_gate(
    const float* __restrict__ prev, const float* __restrict__ curr,
    const ushort* __restrict__ bfragG, const float* __restrict__ gb1,
    const float* __restrict__ gw2, const float* __restrict__ gb2,
    float* __restrict__ gate2) {
  __shared__ __align__(16) ushort img[8 * PSG];
  __shared__ float redg[64];
  __shared__ float pooled[16];

  int tid = threadIdx.x;
  int lane = tid & 63, w = tid >> 6;
  int bt = blockIdx.x;
  int b = bt >> 8, t = bt & 255;
  int quad = lane >> 4, col = lane & 15;
  int qh = quad >> 1, icb = (quad & 1) * 8;

  // zero image: 8*PSG ushorts = PSG uint4
  for (int i = tid; i < PSG; i += 256) ((uint4*)img)[i] = (uint4){0, 0, 0, 0};
  __syncthreads();

  // stage: pair-interleaved fill, contiguous b64 writes
#pragma unroll
  for (int it = 0; it < 4; ++it) {
#pragma unroll
    for (int e = 0; e < 2; ++e) {
      int W = ((it * 4 + w) * 2 + e) * 64 + lane;  // 0..2047
      int cp = W >> 8, pp = W & 255;
      int l0 = pp * 2;
      const float* src = (cp < 4) ? prev : curr;
      int chb = (cp & 3) * 2;
      const float* p0 = src + ((size_t)(b * NH + chb) * TT + t) * LL + l0;
      float2 fa = *(const float2*)p0;
      float2 fb = *(const float2*)(p0 + TT * LL);
      unsigned lo = (unsigned)f2bfu(fa.x) | ((unsigned)f2bfu(fb.x) << 16);
      unsigned hi = (unsigned)f2bfu(fa.y) | ((unsigned)f2bfu(fb.y) << 16);
      int r = l0 >> 5, x = l0 & 31;
      int slot = (r + 1) * 48 + 8 + x;
      *(uint2*)&img[cp * PSG + slot * 2] = (uint2){lo, hi};
    }
  }
  __syncthreads();

  // K-loop: 5 steps of K=32 (2 taps x 16 ic)
  f32x4 acc[8];
#pragma unroll
  for (int mi = 0; mi < 8; ++mi) acc[mi] = (f32x4){0.f, 0.f, 0.f, 0.f};
  int mtbase = w * 8;
  int ab[8];
#pragma unroll
  for (int mi = 0; mi < 8; ++mi) {
    int mt = mtbase + mi;
    int py = mt >> 1, px = ((mt & 1) << 4) + col;
    ab[mi] = (icb >> 1) * PSG + (py * 48 + 7 + px) * 2;
  }
  const int offE[5] = {0, 2, 49, 96, 98};
  const int offO[5] = {1, 48, 50, 97, 98};  // last = dummy (B zero)
  const s8b* bG = (const s8b*)bfragG;
#pragma unroll
  for (int s = 0; s < 5; ++s) {
    s8b bf = bG[s * 64 + lane];
    int off2 = (qh ? offO[s] : offE[s]) * 2;
#pragma unroll
    for (int mi = 0; mi < 8; ++mi) {
      union { unsigned u[4]; s8b v; } A;
      int a0 = ab[mi] + off2;
#pragma unroll
      for (int p = 0; p < 4; ++p) A.u[p] = *(const unsigned*)&img[a0 + p * PSG];
      acc[mi] = __builtin_amdgcn_mfma_f32_16x16x32_bf16(A.v, bf, acc[mi], 0, 0, 0);
    }
  }

  // pool: mean over 512 pixels of relu(conv + b1), per oc (=col)
  float gb1c = (col < GC) ? gb1[col] : 0.f;
  float s = 0.f;
#pragma unroll
  for (int mi = 0; mi < 8; ++mi)
#pragma unroll
    for (int r = 0; r < 4; ++r) s += fmaxf(acc[mi][r] + gb1c, 0.f);
  s += __shfl_down(s, 16, 64);
  s += __shfl_down(s, 32, 64);
  if (lane < 16) redg[w * 16 + lane] = s;
  __syncthreads();
  if (tid < 16)
    pooled[tid] = (redg[tid] + redg[16 + tid] + redg[32 + tid] + redg[48 + tid]) *
                  (1.0f / (float)LL);
  __syncthreads();
  if (tid < 16) {
    float z = gb2[tid];
#pragma unroll
    for (int i = 0; i < GC; ++i) z = fmaf(pooled[i], gw2[tid * GC + i], z);
    gate2[(b * CC + tid) * TT + t] = 1.f / (1.f + __expf(-z));
  }
}

// ---------------------------------------------------------------------------
// K2a: per-chunk sums of attn*gate (8 chunks of 32 t). Gate applied inline.
__global__ __launch_bounds__(256) void k_cumA(const float* __restrict__ prev,
                                              const float* __restrict__ curr,
                                              const float* __restrict__ gate2,
                                              float* __restrict__ csum) {
  int idx = blockIdx.x * 256 + threadIdx.x;
  int l = idx & 511, tc = (idx >> 9) & 7, c = (idx >> 12) & 15, b = idx >> 16;
  const float* src = (c < NH) ? prev : curr;
  const float* a = src + ((size_t)(b * NH + (c & 7)) * TT + tc * 32) * LL + l;
  const float* g = gate2 + (b * CC + c) * TT + tc * 32;
  float s = 0.f;
#pragma unroll 8
  for (int j = 0; j < 32; ++j) s = fmaf(a[(size_t)j * LL], g[j], s);
  csum[((b * CC + c) * 8 + tc) * LL + l] = s;
}

// K2b: exclusive scan within chunk (gate inline) + chunk-offset; writes bf16.
__global__ __launch_bounds__(256) void k_cumB(const float* __restrict__ prev,
                                              const float* __restrict__ curr,
                                              const float* __restrict__ gate2,
                                              const float* __restrict__ csum,
                                              ushort* __restrict__ cum) {
  int idx = blockIdx.x * 256 + threadIdx.x;
  int l = idx & 511, tc = (idx >> 9) & 7, c = (idx >> 12) & 15, b = idx >> 16;
  float run = 0.f;
  const float* cs = csum + ((b * CC + c) * 8) * LL + l;
  for (int u = 0; u < tc; ++u) run += cs[u * LL];
  const float* src = (c < NH) ? prev : curr;
  const float* a = src + ((size_t)(b * NH + (c & 7)) * TT + tc * 32) * LL + l;
  const float* g = gate2 + (b * CC + c) * TT + tc * 32;
  ushort* o = cum + ((size_t)(b * CC + c) * TT + tc * 32) * LL + l;
#pragma unroll 4
  for (int j = 0; j < 32; ++j) {
    o[(size_t)j * LL] = f2bfu(run);  // exclusive
    run = fmaf(a[(size_t)j * LL], g[j], run);
  }
}

// ---------------------------------------------------------------------------
// K3: MFMA implicit-GEMM 5x5 conv 16->32 (+bias+relu), mask, 1x1 proj MFMA,
// BN-sum accumulation. One block = one (b,t) image.
__global__ __launch_bounds__(256, 2) void k_cov(
    const ushort* __restrict__ cum, const ushort* __restrict__ bfrag,
    const ushort* __restrict__ pwf, const float* __restrict__ cb,
    const int* __restrict__ mask, float* __restrict__ out,
    float* __restrict__ sums) {
  __shared__ __align__(16) ushort img[8 * PSC];
  __shared__ __align__(16) ushort scr[4 * 640];   // per wave 32 oc * 20
  __shared__ float redp[128];
  __shared__ float redc[4];

  int tid = threadIdx.x;
  int lane = tid & 63, w = tid >> 6;
  int bt = blockIdx.x;
  int b = bt >> 8, t = bt & 255;
  int quad = lane >> 4, col = lane & 15;
  int qh = quad >> 1, icb = (quad & 1) * 8;

  // zero image: 8*PSC ushorts = PSC uint4
  for (int i = tid; i < PSC; i += 256) ((uint4*)img)[i] = (uint4){0, 0, 0, 0};
  __syncthreads();

  // stage (bf16 pair-interleave, contiguous b64 writes)
#pragma unroll
  for (int it = 0; it < 4; ++it) {
#pragma unroll
    for (int e = 0; e < 2; ++e) {
      int W = ((it * 4 + w) * 2 + e) * 64 + lane;  // 0..2047
      int cp = W >> 8, pp = W & 255;
      int l0 = pp * 2;
      const ushort* p0 = cum + ((size_t)(b * CC + cp * 2) * TT + t) * LL + l0;
      unsigned a = *(const unsigned*)p0;
      unsigned bb2 = *(const unsigned*)(p0 + TT * LL);
      unsigned lo = (a & 0xFFFFu) | (bb2 << 16);
      unsigned hi = (a >> 16) | (bb2 & 0xFFFF0000u);
      int r = l0 >> 5, x = l0 & 31;
      int slot = (r + 2) * 48 + 8 + x;
      *(uint2*)&img[cp * PSC + slot * 2] = (uint2){lo, hi};
    }
  }
  __syncthreads();

  // K-loop: 13 steps of K=32 (2 taps x 16 ic)
  f32x4 acc[8][2];
#pragma unroll
  for (int mi = 0; mi < 8; ++mi) {
    acc[mi][0] = (f32x4){0.f, 0.f, 0.f, 0.f};
    acc[mi][1] = (f32x4){0.f, 0.f, 0.f, 0.f};
  }
  int mtbase = w * 8;
  int ab[8];
#pragma unroll
  for (int mi = 0; mi < 8; ++mi) {
    int mt = mtbase + mi;
    int py = mt >> 1, px = ((mt & 1) << 4) + col;
    ab[mi] = (icb >> 1) * PSC + (py * 48 + 6 + px) * 2;
  }
  const int offE[13] = {0, 2, 4, 49, 51, 96, 98, 100, 145, 147, 192, 194, 196};
  const int offO[13] = {1, 3, 48, 50, 52, 97, 99, 144, 146, 148, 193, 195, 196};
  const s8b* bfr = (const s8b*)bfrag;
#pragma unroll
  for (int s = 0; s < 13; ++s) {
    s8b bf0 = bfr[(s * 2) * 64 + lane];
    s8b bf1 = bfr[(s * 2 + 1) * 64 + lane];
    int off2 = (qh ? offO[s] : offE[s]) * 2;
#pragma unroll
    for (int mi = 0; mi < 8; ++mi) {
      union { unsigned u[4]; s8b v; } A;
      int a0 = ab[mi] + off2;
#pragma unroll
      for (int p = 0; p < 4; ++p) A.u[p] = *(const unsigned*)&img[a0 + p * PSC];
      acc[mi][0] = __builtin_amdgcn_mfma_f32_16x16x32_bf16(A.v, bf0, acc[mi][0], 0, 0, 0);
      acc[mi][1] = __builtin_amdgcn_mfma_f32_16x16x32_bf16(A.v, bf1, acc[mi][1], 0, 0, 0);
    }
  }

  // epilogue: wave-private scr round-trip (C-layout -> A-layout), proj MFMA,
  // mask, store, BN partials. scr row = oc (stride 20), cols = 16 pixels.
  int wb = w * 640;
  float cb0 = cb[col], cb1 = cb[col + 16];
  s8b pf = ((const s8b*)pwf)[lane];
  float psum = 0.f, psq = 0.f, pcnt = 0.f;
  float* outbase = out + ((size_t)(b * NH + col) * TT + t) * LL;  // col<8 only
  const int* mrow = mask + b * LL;
#pragma unroll
  for (int mi = 0; mi < 8; ++mi) {
    int mt = mtbase + mi;
    ushort w0[4], w1[4];
#pragma unroll
    for (int r = 0; r < 4; ++r) {
      w0[r] = f2bfu(fmaxf(acc[mi][0][r] + cb0, 0.f));
      w1[r] = f2bfu(fmaxf(acc[mi][1][r] + cb1, 0.f));
    }
    uint2 pk0, pk1;
    __builtin_memcpy(&pk0, w0, 8);
    __builtin_memcpy(&pk1, w1, 8);
    *(uint2*)&scr[wb + col * 20 + quad * 4] = pk0;          // oc=col
    *(uint2*)&scr[wb + (col + 16) * 20 + quad * 4] = pk1;   // oc=col+16
    ushort u[8];
#pragma unroll
    for (int e = 0; e < 8; ++e) u[e] = scr[wb + (quad * 8 + e) * 20 + col];
    s8b a2;
    __builtin_memcpy(&a2, u, 16);
    f32x4 zero = {0.f, 0.f, 0.f, 0.f};
    f32x4 d2 = __builtin_amdgcn_mfma_f32_16x16x32_bf16(a2, pf, zero, 0, 0, 0);
    int4 m4 = *(const int4*)(mrow + mt * 16 + quad * 4);
    float k0 = m4.x ? 0.f : 1.f;
    float k1 = m4.y ? 0.f : 1.f;
    float k2 = m4.z ? 0.f : 1.f;
    float k3 = m4.w ? 0.f : 1.f;
    if (col < NH) {
      float* op = outbase + mt * 16 + quad * 4;
      float v0 = d2[0] * k0; op[0] = v0; psum += v0; psq += v0 * v0;
      float v1 = d2[1] * k1; op[1] = v1; psum += v1; psq += v1 * v1;
      float v2 = d2[2] * k2; op[2] = v2; psum += v2; psq += v2 * v2;
      float v3 = d2[3] * k3; op[3] = v3; psum += v3; psq += v3 * v3;
    }
    if (col == 0) pcnt += k0 + k1 + k2 + k3;
  }

  psum += __shfl_down(psum, 16, 64); psum += __shfl_down(psum, 32, 64);
  psq  += __shfl_down(psq, 16, 64);  psq  += __shfl_down(psq, 32, 64);
  pcnt += __shfl_down(pcnt, 16, 64); pcnt += __shfl_down(pcnt, 32, 64);
  if (lane < 16) {
    redp[(w * 16 + lane) * 2] = psum;
    redp[(w * 16 + lane) * 2 + 1] = psq;
    if (lane == 0) redc[w] = pcnt;
  }
  __syncthreads();
  if (tid < 17) {
    float v;
    if (tid < 8) {
      v = redp[tid * 2] + redp[(16 + tid) * 2] + redp[(32 + tid) * 2] + redp[(48 + tid) * 2];
    } else if (tid < 16) {
      int nh = tid - 8;
      v = redp[nh * 2 + 1] + redp[(16 + nh) * 2 + 1] + redp[(32 + nh) * 2 + 1] + redp[(48 + nh) * 2 + 1];
    } else {
      v = redc[0] + redc[1] + redc[2] + redc[3];
    }
    atomicAdd(&sums[tid], v);
  }
}

// ---------------------------------------------------------------------------
// K4: masked BN normalize in-place.
__global__ __launch_bounds__(256) void k_bn(
    float* __restrict__ out, const float* __restrict__ sums,
    const int* __restrict__ mask, const float* __restrict__ gamma,
    const float* __restrict__ beta) {
  __shared__ float sc[NH], sh[NH];
  int tid = threadIdx.x;
  if (tid < NH) {
    float cnt = sums[16];
    float mean = sums[tid] / cnt;
    float var = sums[NH + tid] / cnt - mean * mean;
    float inv = rsqrtf(var + 1e-5f) * gamma[tid];
    sc[tid] = inv;
    sh[tid] = fmaf(-mean, inv, beta[tid]);
  }
  __syncthreads();
  size_t e = ((size_t)blockIdx.x * 256 + tid) * 4;
  int l = (int)(e & (LL - 1));
  int bn = (int)(e >> 17);
  int n = bn & 7, b = bn >> 3;
  const int4 mv = *(const int4*)(mask + b * LL + l);
  float4 v = *(float4*)(out + e);
  float s = sc[n], h = sh[n];
  v.x = mv.x ? v.x : fmaf(v.x, s, h);
  v.y = mv.y ? v.y : fmaf(v.y, s, h);
  v.z = mv.z ? v.z : fmaf(v.z, s, h);
  v.w = mv.w ? v.w : fmaf(v.w, s, h);
  *(float4*)(out + e) = v;
}

// ---------------------------------------------------------------------------
extern "C" void kernel_launch(void* const* d_in, const int* in_sizes, int n_in,
                              void* d_out, int out_size, void* d_ws, size_t ws_size,
                              hipStream_t stream) {
  const float* prev   = (const float*)d_in[0];
  const int*   mask   = (const int*)d_in[1];
  const float* curr   = (const float*)d_in[3];
  const float* conv_w = (const float*)d_in[5];
  const float* conv_b = (const float*)d_in[6];
  const float* proj_w = (const float*)d_in[7];
  const float* g_w1   = (const float*)d_in[8];
  const float* g_b1   = (const float*)d_in[9];
  const float* g_w2   = (const float*)d_in[10];
  const float* g_b2   = (const float*)d_in[11];
  const float* bn_g   = (const float*)d_in[12];
  const float* bn_b   = (const float*)d_in[13];
  float* out = (float*)d_out;

  char* ws = (char*)d_ws;
  ushort* bfrag  = (ushort*)(ws);                    // 26624 B
  ushort* pwf    = (ushort*)(ws + 26624);            // 1024 B
  ushort* bfragG = (ushort*)(ws + 27648);            // 5120 B
  float*  sums   = (float*)(ws + 32768);             // 68 B
  float*  gate2  = (float*)(ws + 36864);             // 131072 B  [b][c][t]
  ushort* cum    = (ushort*)(ws + 36864 + 131072);   // 33554432 B
  float*  csum   = (float*)(ws + 36864 + 131072 + 33554432);  // 2097152 B

  k_gen<<<64, 256, 0, stream>>>(conv_w, proj_w, g_w1, bfrag, pwf, bfragG, sums);
  k_gate<<<BB * TT, 256, 0, stream>>>(prev, curr, bfragG, g_b1, g_w2, g_b2, gate2);
  k_cumA<<<2048, 256, 0, stream>>>(prev, curr, gate2, csum);
  k_cumB<<<2048, 256, 0, stream>>>(prev, curr, gate2, csum, cum);
  k_cov<<<BB * TT, 256, 0, stream>>>(cum, bfrag, pwf, conv_b, mask, out, sums);
  k_bn<<<(BB * NH * TT * LL) / (256 * 4), 256, 0, stream>>>(out, sums, mask, bn_g, bn_b);
}